// Round 1
// baseline (743.683 us; speedup 1.0000x reference)
//
#include <hip/hip_runtime.h>

// GsumLayer: out[b] = a[b] @ x[b], B=8, N=4096, D=32, fp32.
// Memory-bound: a (536 MB) streamed once. fp32 vector FMA path (no fp32 MFMA on CDNA4).
//
// Input order per setup_inputs(): d_in[0] = x [B,N,D], d_in[1] = a [B,N,N].

#define GN 4096
#define GD 32
#define ROWS 64   // rows per block
#define BK 64     // K-chunk
#define APAD 4    // pad As leading dim to 68 floats -> conflict-free b128 reads

__global__ __launch_bounds__(256, 2) void gsum_kernel(
    const float* __restrict__ x,
    const float* __restrict__ a,
    float* __restrict__ out)
{
    __shared__ float As[ROWS][BK + APAD];  // 64 x 68 x 4B = 17408 B
    __shared__ float Xs[BK][GD];           // 64 x 32 x 4B =  8192 B

    const int t    = threadIdx.x;
    const int b    = blockIdx.x >> 6;      // 64 row-tiles per batch
    const int tile = blockIdx.x & 63;
    const long long row0 = (long long)tile * ROWS;

    const float* Ab = a   + ((long long)b * GN + row0) * GN;
    const float* Xb = x   + (long long)b * GN * GD;
    float*       Ob = out + ((long long)b * GN + row0) * GD;

    // compute mapping: thread -> (row r and r+32, col group g of 4)
    const int g = t & 7;
    const int r = t >> 3;

    // staging mapping: sr = row / k-row index (0..63), sc = 4-float column slot
    const int sr = t >> 2;
    const int sc = (t & 3) * 4;

    float4 acc0 = {0.f, 0.f, 0.f, 0.f};
    float4 acc1 = {0.f, 0.f, 0.f, 0.f};

    for (int k0 = 0; k0 < GN; k0 += BK) {
        __syncthreads();

        // ---- stage A tile: rows sr, 16 contiguous floats per thread, coalesced per instr
        {
            const float* Arow = Ab + (long long)sr * GN + k0;
            #pragma unroll
            for (int i = 0; i < 4; ++i) {
                float4 v = *(const float4*)(Arow + sc + i * 16);
                *(float4*)&As[sr][sc + i * 16] = v;
            }
        }
        // ---- stage X chunk: k-row sr, 8 floats per thread
        {
            const float* Xrow = Xb + (long long)(k0 + sr) * GD;
            float4 v0 = *(const float4*)(Xrow + sc);
            float4 v1 = *(const float4*)(Xrow + 16 + sc);
            *(float4*)&Xs[sr][sc]      = v0;
            *(float4*)&Xs[sr][16 + sc] = v1;
        }

        __syncthreads();

        // ---- compute: per 4 k: 2 A b128 + 4 X b128 + 32 FMA
        #pragma unroll
        for (int kk = 0; kk < BK; kk += 4) {
            float4 a0 = *(const float4*)&As[r][kk];
            float4 a1 = *(const float4*)&As[r + 32][kk];
            #pragma unroll
            for (int j = 0; j < 4; ++j) {
                float4 xv = *(const float4*)&Xs[kk + j][g * 4];
                float aj0 = (j == 0) ? a0.x : (j == 1) ? a0.y : (j == 2) ? a0.z : a0.w;
                float aj1 = (j == 0) ? a1.x : (j == 1) ? a1.y : (j == 2) ? a1.z : a1.w;
                acc0.x += aj0 * xv.x; acc0.y += aj0 * xv.y;
                acc0.z += aj0 * xv.z; acc0.w += aj0 * xv.w;
                acc1.x += aj1 * xv.x; acc1.y += aj1 * xv.y;
                acc1.z += aj1 * xv.z; acc1.w += aj1 * xv.w;
            }
        }
    }

    // ---- epilogue: 2 coalesced float4 stores per thread
    *(float4*)(Ob + (long long)r        * GD + g * 4) = acc0;
    *(float4*)(Ob + (long long)(r + 32) * GD + g * 4) = acc1;
}

extern "C" void kernel_launch(void* const* d_in, const int* in_sizes, int n_in,
                              void* d_out, int out_size, void* d_ws, size_t ws_size,
                              hipStream_t stream) {
    const float* x = (const float*)d_in[0];  // [B, N, D]
    const float* a = (const float*)d_in[1];  // [B, N, N]
    float* out = (float*)d_out;              // [B, N, D]

    const int B = 8;
    const int tiles_per_batch = GN / ROWS;   // 64
    dim3 grid(B * tiles_per_batch);          // 512 blocks
    dim3 block(256);
    gsum_kernel<<<grid, block, 0, stream>>>(x, a, out);
}